// Round 1
// baseline (31979.770 us; speedup 1.0000x reference)
//
#include <hip/hip_runtime.h>
#include <math.h>

// LSTM: B=64, T=256, D=H=O=1024. fp32 everywhere (correctness baseline round).
#define Bb 64
#define Tt 256
#define Dd 1024
#define Hh 1024
#define Oo 1024
#define G4 4096  // 4*H

// ---------------- grid barrier (persistent-kernel, agent scope) ----------------
__device__ __forceinline__ void gbar(unsigned* cnt, unsigned* gen, unsigned nb) {
  __syncthreads();
  if (threadIdx.x == 0) {
    __threadfence();  // publish this block's global stores device-wide
    unsigned g = __hip_atomic_load(gen, __ATOMIC_RELAXED, __HIP_MEMORY_SCOPE_AGENT);
    if (__hip_atomic_fetch_add(cnt, 1u, __ATOMIC_ACQ_REL, __HIP_MEMORY_SCOPE_AGENT) == nb - 1u) {
      __hip_atomic_store(cnt, 0u, __ATOMIC_RELAXED, __HIP_MEMORY_SCOPE_AGENT);
      __hip_atomic_store(gen, g + 1u, __ATOMIC_RELEASE, __HIP_MEMORY_SCOPE_AGENT);
    } else {
      unsigned spins = 0;
      while (__hip_atomic_load(gen, __ATOMIC_ACQUIRE, __HIP_MEMORY_SCOPE_AGENT) == g) {
        __builtin_amdgcn_s_sleep(8);
        if (++spins > (1u << 18)) break;  // safety valve: never hang the container
      }
    }
  }
  __syncthreads();
}

// ---------------- gx = x @ [Wi|Wf|Wj|Wo] + b  ->  gxT[t][g][b] ----------------
// grid (64 gtiles, 256 t), 256 thr. Tile 64b x 64g, thread 4b x 4g, full K.
// Global-direct register GEMM: A rows (x) are k-contiguous, W rows g-contiguous.
__global__ __launch_bounds__(256) void gx_gemm(
    const float* __restrict__ x,
    const float* __restrict__ W0, const float* __restrict__ W1,
    const float* __restrict__ W2, const float* __restrict__ W3,
    const float* __restrict__ bi, const float* __restrict__ bf_,
    const float* __restrict__ bj, const float* __restrict__ bo,
    float* __restrict__ gxT) {
  const int gt = blockIdx.x;          // 0..63 (global gate-col tile of 64)
  const int t  = blockIdx.y;          // 0..255
  const int q  = gt >> 4;             // which gate (16 tiles per gate)
  const int col0 = (gt & 15) << 6;    // col base within that gate's W
  const float* __restrict__ Wq = (q == 0) ? W0 : (q == 1) ? W1 : (q == 2) ? W2 : W3;
  const float* __restrict__ bq = (q == 0) ? bi : (q == 1) ? bf_ : (q == 2) ? bj : bo;

  const int bb = threadIdx.x & 15, gg = threadIdx.x >> 4;
  const int b0 = bb << 2, g0 = gg << 2;

  const float* __restrict__ xr0 = x + ((size_t)(b0 + 0) * Tt + t) * Dd;
  const float* __restrict__ xr1 = x + ((size_t)(b0 + 1) * Tt + t) * Dd;
  const float* __restrict__ xr2 = x + ((size_t)(b0 + 2) * Tt + t) * Dd;
  const float* __restrict__ xr3 = x + ((size_t)(b0 + 3) * Tt + t) * Dd;
  const float* __restrict__ wp = Wq + col0 + g0;

  float bias[4];
  *(float4*)bias = *(const float4*)(bq + col0 + g0);
  float acc[4][4];  // [j: g-offset][i: b-offset]
#pragma unroll
  for (int j = 0; j < 4; ++j)
#pragma unroll
    for (int i = 0; i < 4; ++i) acc[j][i] = bias[j];

  for (int k0 = 0; k0 < Dd; k0 += 4) {
    float a[4][4];  // [i][kk]
    *(float4*)a[0] = *(const float4*)(xr0 + k0);
    *(float4*)a[1] = *(const float4*)(xr1 + k0);
    *(float4*)a[2] = *(const float4*)(xr2 + k0);
    *(float4*)a[3] = *(const float4*)(xr3 + k0);
    float u[4][4];  // [kk][j]
#pragma unroll
    for (int kk = 0; kk < 4; ++kk)
      *(float4*)u[kk] = *(const float4*)(wp + (size_t)(k0 + kk) * Hh);
#pragma unroll
    for (int kk = 0; kk < 4; ++kk)
#pragma unroll
      for (int j = 0; j < 4; ++j)
#pragma unroll
        for (int i = 0; i < 4; ++i) acc[j][i] += a[i][kk] * u[kk][j];
  }

#pragma unroll
  for (int j = 0; j < 4; ++j) {
    float4 v = {acc[j][0], acc[j][1], acc[j][2], acc[j][3]};
    *(float4*)(gxT + ((size_t)t * G4 + (size_t)(gt * 64 + g0 + j)) * Bb + b0) = v;
  }
}

// ---------------- persistent recurrence ----------------
// 256 blocks x 256 thr. Block nb owns state cols s0=4*nb..+4 (all 4 gates ->
// self-contained cell update, ONE grid barrier per step).
// GEMM thread map: bb(16) x q(4) x ws(4 = wave k-split of K=1024 into 256).
// ht layout [k][b] (b fast) -> float4 A loads. Partials reduced through LDS.
template <bool FUSED>
__global__ __launch_bounds__(256) void lstm_rec(
    const float* __restrict__ x, const float* __restrict__ h0,
    const float* __restrict__ c0,
    const float* __restrict__ U0, const float* __restrict__ U1,
    const float* __restrict__ U2, const float* __restrict__ U3,
    const float* __restrict__ W0, const float* __restrict__ W1,
    const float* __restrict__ W2, const float* __restrict__ W3,
    const float* __restrict__ bi, const float* __restrict__ bf_,
    const float* __restrict__ bj, const float* __restrict__ bo,
    const float* __restrict__ gxT, float* __restrict__ hsT,
    float* ht0, float* ht1, unsigned* bar) {
  const int nb = blockIdx.x;
  const int s0 = nb << 2;
  const int tid = threadIdx.x;
  const int bb = tid & 15, q = (tid >> 4) & 3, ws = tid >> 6;
  const int b0 = bb << 2;
  const int kbeg = ws << 8, kend = kbeg + 256;

  const float* __restrict__ Uq =
      ((q == 0) ? U0 : (q == 1) ? U1 : (q == 2) ? U2 : U3) + s0;
  const float* __restrict__ Wq =
      ((q == 0) ? W0 : (q == 1) ? W1 : (q == 2) ? W2 : W3) + s0;

  // update-phase mapping: one (n,b) cell per thread
  const int un = tid >> 6, ub = tid & 63;
  float c = c0[(size_t)ub * Hh + s0 + un];
  ht0[(size_t)(s0 + un) * Bb + ub] = h0[(size_t)ub * Hh + s0 + un];
  float bu[4];
  bu[0] = bi[s0 + un]; bu[1] = bf_[s0 + un]; bu[2] = bj[s0 + un]; bu[3] = bo[s0 + un];

  __shared__ float G[4 * 16 * 68];  // [ws][16 gate-cols][64b + pad4]

  gbar(bar, bar + 1, gridDim.x);

  for (int t = 0; t < Tt; ++t) {
    const float* __restrict__ A = (t & 1) ? ht1 : ht0;
    float* __restrict__ Anext = (t & 1) ? ht0 : ht1;

    float acc[4][4] = {};  // [j: state-col offset][i: b offset]
#pragma unroll 8
    for (int k = kbeg; k < kend; ++k) {
      float4 av = *(const float4*)(A + (size_t)k * Bb + b0);
      float4 uv = *(const float4*)(Uq + (size_t)k * Hh);
      float aa[4] = {av.x, av.y, av.z, av.w};
      float uu[4] = {uv.x, uv.y, uv.z, uv.w};
#pragma unroll
      for (int j = 0; j < 4; ++j)
#pragma unroll
        for (int i = 0; i < 4; ++i) acc[j][i] += aa[i] * uu[j];
    }

    if (FUSED) {  // fold x@W for this step in (small-workspace fallback)
      const float* __restrict__ xr0 = x + ((size_t)(b0 + 0) * Tt + t) * Dd;
      const float* __restrict__ xr1 = x + ((size_t)(b0 + 1) * Tt + t) * Dd;
      const float* __restrict__ xr2 = x + ((size_t)(b0 + 2) * Tt + t) * Dd;
      const float* __restrict__ xr3 = x + ((size_t)(b0 + 3) * Tt + t) * Dd;
      for (int k0 = kbeg; k0 < kend; k0 += 4) {
        float a[4][4];
        *(float4*)a[0] = *(const float4*)(xr0 + k0);
        *(float4*)a[1] = *(const float4*)(xr1 + k0);
        *(float4*)a[2] = *(const float4*)(xr2 + k0);
        *(float4*)a[3] = *(const float4*)(xr3 + k0);
        float u[4][4];
#pragma unroll
        for (int kk = 0; kk < 4; ++kk)
          *(float4*)u[kk] = *(const float4*)(Wq + (size_t)(k0 + kk) * Hh);
#pragma unroll
        for (int kk = 0; kk < 4; ++kk)
#pragma unroll
          for (int j = 0; j < 4; ++j)
#pragma unroll
            for (int i = 0; i < 4; ++i) acc[j][i] += a[i][kk] * u[kk][j];
      }
    }

#pragma unroll
    for (int j = 0; j < 4; ++j) {
      float4 v = {acc[j][0], acc[j][1], acc[j][2], acc[j][3]};
      *(float4*)&G[(size_t)(ws * 16 + q * 4 + j) * 68 + b0] = v;
    }
    __syncthreads();

    // ---- block-local cell update for (n = s0+un, b = ub) ----
    float g4[4];
#pragma unroll
    for (int qq = 0; qq < 4; ++qq) {
      float s = G[(size_t)(0 * 16 + qq * 4 + un) * 68 + ub] +
                G[(size_t)(1 * 16 + qq * 4 + un) * 68 + ub] +
                G[(size_t)(2 * 16 + qq * 4 + un) * 68 + ub] +
                G[(size_t)(3 * 16 + qq * 4 + un) * 68 + ub];
      if (FUSED)
        s += bu[qq];
      else
        s += gxT[((size_t)t * G4 + (size_t)qq * Hh + s0 + un) * Bb + ub];
      g4[qq] = s;
    }
    float i_ = 1.f / (1.f + __expf(-g4[0]));
    float f_ = 1.f / (1.f + __expf(-g4[1]));
    float j_ = tanhf(g4[2]);
    float o_ = 1.f / (1.f + __expf(-g4[3]));
    c = f_ * c + i_ * j_;
    float h = o_ * tanhf(c);
    Anext[(size_t)(s0 + un) * Bb + ub] = h;
    hsT[((size_t)t * Hh + s0 + un) * Bb + ub] = h;

    gbar(bar, bar + 1, gridDim.x);
  }
}

// ---------------- y = hs @ Wy + by ----------------
// grid (16 otiles, 256 t). A = hsT[t] is [n][b] (b fast) -> float4 loads.
__global__ __launch_bounds__(256) void y_gemm(const float* __restrict__ hsT,
                                              const float* __restrict__ Wy,
                                              const float* __restrict__ by,
                                              float* __restrict__ y) {
  const int ot = blockIdx.x;  // 0..15
  const int t  = blockIdx.y;  // 0..255
  const int o0 = (ot << 6) + ((threadIdx.x >> 4) << 2);
  const int b0 = (threadIdx.x & 15) << 2;

  float bias[4];
  *(float4*)bias = *(const float4*)(by + o0);
  float acc[4][4];  // [i: b][j: o]
#pragma unroll
  for (int i = 0; i < 4; ++i)
#pragma unroll
    for (int j = 0; j < 4; ++j) acc[i][j] = bias[j];

  const float* __restrict__ Ap = hsT + (size_t)t * Hh * Bb;
  for (int k = 0; k < Hh; ++k) {
    float4 av = *(const float4*)(Ap + (size_t)k * Bb + b0);
    float4 uv = *(const float4*)(Wy + (size_t)k * Oo + o0);
    float aa[4] = {av.x, av.y, av.z, av.w};
    float uu[4] = {uv.x, uv.y, uv.z, uv.w};
#pragma unroll
    for (int i = 0; i < 4; ++i)
#pragma unroll
      for (int j = 0; j < 4; ++j) acc[i][j] += aa[i] * uu[j];
  }

#pragma unroll
  for (int i = 0; i < 4; ++i) {
    float4 v = {acc[i][0], acc[i][1], acc[i][2], acc[i][3]};
    *(float4*)(y + ((size_t)(b0 + i) * Tt + t) * Oo + o0) = v;
  }
}

extern "C" void kernel_launch(void* const* d_in, const int* in_sizes, int n_in,
                              void* d_out, int out_size, void* d_ws, size_t ws_size,
                              hipStream_t stream) {
  const float* x  = (const float*)d_in[0];
  const float* h0 = (const float*)d_in[1];
  const float* c0 = (const float*)d_in[2];
  const float* W0 = (const float*)d_in[3];
  const float* W1 = (const float*)d_in[4];
  const float* W2 = (const float*)d_in[5];
  const float* W3 = (const float*)d_in[6];
  const float* U0 = (const float*)d_in[7];
  const float* U1 = (const float*)d_in[8];
  const float* U2 = (const float*)d_in[9];
  const float* U3 = (const float*)d_in[10];
  const float* bi = (const float*)d_in[11];
  const float* bf_ = (const float*)d_in[12];
  const float* bj = (const float*)d_in[13];
  const float* bo = (const float*)d_in[14];
  const float* Wy = (const float*)d_in[15];
  const float* by = (const float*)d_in[16];
  float* y = (float*)d_out;

  const size_t gx_elems = (size_t)Tt * G4 * Bb;   // 67,108,864 floats (256 MB)
  const size_t hs_elems = (size_t)Tt * Hh * Bb;   // 16,777,216 floats (64 MB)
  const size_t ht_elems = (size_t)Hh * Bb;        // 65,536 floats
  const size_t need_full = (gx_elems + hs_elems + 2 * ht_elems) * 4 + 256;
  const bool fused = (ws_size < need_full);  // small-workspace fallback

  float* base = (float*)d_ws;
  float *gxT, *hsT, *ht0, *ht1;
  unsigned* bar;
  if (!fused) {
    gxT = base;
    hsT = gxT + gx_elems;
    ht0 = hsT + hs_elems;
    ht1 = ht0 + ht_elems;
    bar = (unsigned*)(ht1 + ht_elems);
  } else {
    gxT = nullptr;
    hsT = base;
    ht0 = hsT + hs_elems;
    ht1 = ht0 + ht_elems;
    bar = (unsigned*)(ht1 + ht_elems);
  }

  hipMemsetAsync(bar, 0, 64, stream);  // barrier {cnt, gen} = 0 each launch

  if (!fused) {
    dim3 gg(64, 256);
    gx_gemm<<<gg, 256, 0, stream>>>(x, W0, W1, W2, W3, bi, bf_, bj, bo, gxT);
    lstm_rec<false><<<256, 256, 0, stream>>>(x, h0, c0, U0, U1, U2, U3, W0, W1,
                                             W2, W3, bi, bf_, bj, bo, gxT, hsT,
                                             ht0, ht1, bar);
  } else {
    lstm_rec<true><<<256, 256, 0, stream>>>(x, h0, c0, U0, U1, U2, U3, W0, W1,
                                            W2, W3, bi, bf_, bj, bo, gxT, hsT,
                                            ht0, ht1, bar);
  }

  dim3 gy(16, 256);
  y_gemm<<<gy, 256, 0, stream>>>(hsT, Wy, by, y);
}

// Round 6
// 25507.812 us; speedup vs baseline: 1.2537x; 1.2537x over previous
//
#include <hip/hip_runtime.h>
#include <math.h>

// LSTM: B=64, T=256, D=H=O=1024. fp32 in/out.
// R5: crashes R1/R2/R4 attributed to WORKSPACE OVERFLOW (all required >=320MB
// of d_ws unconditionally; R0 passed via its 67.6MB fused fallback). This
// round: fused recurrence (no gxT), U AND W packed into per-block contiguous
// 64KB global slices (L2-resident). Tiered layouts chosen at launch from the
// REAL ws_size; guaranteed tier needs exactly R0's proven 67,633,216 bytes.
// LDS: 4.3 KB. Static shared <= R0-proven profile.
#define Bb 64
#define Tt 256
#define Dd 1024
#define Hh 1024
#define Oo 1024

// ---------------- grid barrier (persistent-kernel, agent scope) ----------------
__device__ __forceinline__ void gbar(unsigned* cnt, unsigned* gen, unsigned nb) {
  __syncthreads();
  if (threadIdx.x == 0) {
    __threadfence();
    unsigned g = __hip_atomic_load(gen, __ATOMIC_RELAXED, __HIP_MEMORY_SCOPE_AGENT);
    if (__hip_atomic_fetch_add(cnt, 1u, __ATOMIC_ACQ_REL, __HIP_MEMORY_SCOPE_AGENT) == nb - 1u) {
      __hip_atomic_store(cnt, 0u, __ATOMIC_RELAXED, __HIP_MEMORY_SCOPE_AGENT);
      __hip_atomic_store(gen, g + 1u, __ATOMIC_RELEASE, __HIP_MEMORY_SCOPE_AGENT);
    } else {
      unsigned spins = 0;
      while (__hip_atomic_load(gen, __ATOMIC_ACQUIRE, __HIP_MEMORY_SCOPE_AGENT) == g) {
        __builtin_amdgcn_s_sleep(8);
        if (++spins > (1u << 18)) break;  // safety valve
      }
    }
  }
  __syncthreads();
}

__device__ __forceinline__ unsigned short f32_to_bf16(float f) {
  unsigned u = __float_as_uint(f);
  u += 0x7FFFu + ((u >> 16) & 1u);  // round to nearest even
  return (unsigned short)(u >> 16);
}

// ---------------- persistent fused recurrence ----------------
// 256 blocks x 256 thr (1 block/CU). Block nb owns state cols s0=4*nb..+3.
// Per step: g = x_t @ W[:,s0..] + h @ U[:,s0..] + b, for all 4 gates.
// wave q = gate; lane = ws*16+bb (ws = 4-way k-split, bb = b-quad).
// PACKED: U/W slices pre-packed to contiguous Uc/Wc (64KB each per block,
// L2-resident) -> no line-amplified HBM/L3 re-fetch.
// Reduce over ws via shfl_xor(16,32); gate exchange via 4.3KB LDS.
template <bool PACKED, bool HSBF16>
__global__ __launch_bounds__(256) void lstm_fused(
    const float* __restrict__ x, const float* __restrict__ h0,
    const float* __restrict__ c0,
    const float* __restrict__ U0, const float* __restrict__ U1,
    const float* __restrict__ U2, const float* __restrict__ U3,
    const float* __restrict__ W0, const float* __restrict__ W1,
    const float* __restrict__ W2, const float* __restrict__ W3,
    const float* __restrict__ bi, const float* __restrict__ bf_,
    const float* __restrict__ bj, const float* __restrict__ bo,
    void* __restrict__ hsT, float* ht0, float* ht1,
    float* __restrict__ Uc, float* __restrict__ Wc, unsigned* bar) {
  const int nb = blockIdx.x;
  const int s0 = nb << 2;
  const int tid = threadIdx.x;
  const int lane = tid & 63;
  const int q  = tid >> 6;    // wave = gate
  const int ws = lane >> 4;   // k-split slot
  const int bb = lane & 15;   // b-quad
  const int b0 = bb << 2;

  __shared__ float G2[16 * 68];  // [gate*4+col][64 b + pad] : 4.3 KB

  float* __restrict__ Ub = PACKED ? Uc + (size_t)nb * 16384 : nullptr;
  float* __restrict__ Wb = PACKED ? Wc + (size_t)nb * 16384 : nullptr;

  if (PACKED) {
    // pack own U/W slices -> [k][gate*4+col] (private to this block)
#pragma unroll
    for (int it = 0; it < 16; ++it) {
      const int qq = it & 3;
      const int k = ((it >> 2) << 8) + tid;
      const float* __restrict__ Uq =
          ((qq == 0) ? U0 : (qq == 1) ? U1 : (qq == 2) ? U2 : U3) + s0;
      const float* __restrict__ Wq =
          ((qq == 0) ? W0 : (qq == 1) ? W1 : (qq == 2) ? W2 : W3) + s0;
      *(float4*)&Ub[k * 16 + qq * 4] = *(const float4*)(Uq + (size_t)k * Hh);
      *(float4*)&Wb[k * 16 + qq * 4] = *(const float4*)(Wq + (size_t)k * Hh);
    }
  }

  // update-phase mapping: one (n,b) cell per thread
  const int un = tid >> 6, ub = tid & 63;
  float c = c0[(size_t)ub * Hh + s0 + un];
  ht0[(size_t)(s0 + un) * Bb + ub] = h0[(size_t)ub * Hh + s0 + un];
  float bu[4];
  bu[0] = bi[s0 + un]; bu[1] = bf_[s0 + un];
  bu[2] = bj[s0 + un]; bu[3] = bo[s0 + un];

  gbar(bar, bar + 1, gridDim.x);  // publishes Ub/Wb/ht0 (drains vmcnt)

  // direct-path base pointers (fallback tier)
  const float* __restrict__ UqD =
      ((q == 0) ? U0 : (q == 1) ? U1 : (q == 2) ? U2 : U3) + s0 + (size_t)ws * Hh;
  const float* __restrict__ WqD =
      ((q == 0) ? W0 : (q == 1) ? W1 : (q == 2) ? W2 : W3) + s0;

  // x row pointers for W-part (advance with t inside loop)
  const float* __restrict__ xr0 = x + ((size_t)(b0 + 0) * Tt) * Dd + 4 * ws;
  const float* __restrict__ xr1 = x + ((size_t)(b0 + 1) * Tt) * Dd + 4 * ws;
  const float* __restrict__ xr2 = x + ((size_t)(b0 + 2) * Tt) * Dd + 4 * ws;
  const float* __restrict__ xr3 = x + ((size_t)(b0 + 3) * Tt) * Dd + 4 * ws;

  for (int t = 0; t < Tt; ++t) {
    const float* __restrict__ A = (t & 1) ? ht1 : ht0;
    float* __restrict__ Anext = (t & 1) ? ht0 : ht1;

    float acc[4][4] = {};  // [j: col][i: b]

    // ---- U part: h @ U, k' = 4k+ws ----
    {
      const float* __restrict__ Ap = A + (size_t)ws * Bb + b0;
      const float* __restrict__ Up = PACKED ? (Ub + ws * 16 + q * 4) : UqD;
      const size_t ustep = PACKED ? 64 : 4 * (size_t)Hh;
#pragma unroll 8
      for (int k = 0; k < 256; ++k) {
        float4 av = *(const float4*)Ap;
        float4 uv = *(const float4*)Up;
        Ap += 4 * Bb;
        Up += ustep;
        float aa[4] = {av.x, av.y, av.z, av.w};
        float uu[4] = {uv.x, uv.y, uv.z, uv.w};
#pragma unroll
        for (int j = 0; j < 4; ++j)
#pragma unroll
          for (int i = 0; i < 4; ++i) acc[j][i] += aa[i] * uu[j];
      }
    }

    // ---- W part: x_t @ W, d-quads q' = ws + 4j ----
    {
      const size_t xoff = (size_t)t * Dd;
#pragma unroll 4
      for (int j = 0; j < 64; ++j) {
        float a[4][4];  // [i: b][kk]
        *(float4*)a[0] = *(const float4*)(xr0 + xoff + 16 * j);
        *(float4*)a[1] = *(const float4*)(xr1 + xoff + 16 * j);
        *(float4*)a[2] = *(const float4*)(xr2 + xoff + 16 * j);
        *(float4*)a[3] = *(const float4*)(xr3 + xoff + 16 * j);
        float w[4][4];  // [kk][jc]
#pragma unroll
        for (int kk = 0; kk < 4; ++kk) {
          if (PACKED)
            *(float4*)w[kk] = *(const float4*)(Wb + (size_t)(ws * 64 + j * 256 + kk * 16) + q * 4);
          else
            *(float4*)w[kk] = *(const float4*)(WqD + (size_t)(4 * (ws + 4 * j) + kk) * Hh);
        }
#pragma unroll
        for (int kk = 0; kk < 4; ++kk)
#pragma unroll
          for (int jc = 0; jc < 4; ++jc)
#pragma unroll
            for (int i = 0; i < 4; ++i) acc[jc][i] += a[i][kk] * w[kk][jc];
      }
    }

    // ---- in-wave reduce over ws (lane bits 4,5) ----
#pragma unroll
    for (int j = 0; j < 4; ++j)
#pragma unroll
      for (int i = 0; i < 4; ++i) {
        float v = acc[j][i];
        v += __shfl_xor(v, 16);
        v += __shfl_xor(v, 32);
        acc[j][i] = v;
      }
    if (ws == 0) {
#pragma unroll
      for (int j = 0; j < 4; ++j) {
        float4 v = {acc[j][0], acc[j][1], acc[j][2], acc[j][3]};
        *(float4*)&G2[(q * 4 + j) * 68 + b0] = v;
      }
    }
    __syncthreads();

    // ---- block-local cell update for (n = s0+un, b = ub) ----
    float g4[4];
#pragma unroll
    for (int qq = 0; qq < 4; ++qq)
      g4[qq] = G2[(qq * 4 + un) * 68 + ub] + bu[qq];

    float i_ = 1.f / (1.f + __expf(-g4[0]));
    float f_ = 1.f / (1.f + __expf(-g4[1]));
    float j_ = tanhf(g4[2]);
    float o_ = 1.f / (1.f + __expf(-g4[3]));
    c = f_ * c + i_ * j_;
    float h = o_ * tanhf(c);
    Anext[(size_t)(s0 + un) * Bb + ub] = h;
    const size_t hidx = ((size_t)t * Hh + s0 + un) * Bb + ub;
    if (HSBF16)
      ((unsigned short*)hsT)[hidx] = f32_to_bf16(h);
    else
      ((float*)hsT)[hidx] = h;

    gbar(bar, bar + 1, gridDim.x);
  }
}

// ---------------- y = hs @ Wy + by ----------------
// hsT layout [t][n][b] (b fast), fp32 or bf16 (bf16->fp32 via exact bit shift).
template <bool HSBF16>
__global__ __launch_bounds__(256) void y_gemm(const void* __restrict__ hsT,
                                              const float* __restrict__ Wy,
                                              const float* __restrict__ by,
                                              float* __restrict__ y) {
  const int ot = blockIdx.x;  // 0..15
  const int t  = blockIdx.y;  // 0..255
  const int o0 = (ot << 6) + ((threadIdx.x >> 4) << 2);
  const int b0 = (threadIdx.x & 15) << 2;

  float bias[4];
  *(float4*)bias = *(const float4*)(by + o0);
  float acc[4][4];  // [i: b][j: o]
#pragma unroll
  for (int i = 0; i < 4; ++i)
#pragma unroll
    for (int j = 0; j < 4; ++j) acc[i][j] = bias[j];

  const float* __restrict__ Af =
      HSBF16 ? nullptr : (const float*)hsT + (size_t)t * Hh * Bb;
  const unsigned short* __restrict__ Ah =
      HSBF16 ? (const unsigned short*)hsT + (size_t)t * Hh * Bb : nullptr;

  for (int k = 0; k < Hh; ++k) {
    float aa[4];
    if (HSBF16) {
      ushort4 av = *(const ushort4*)(Ah + (size_t)k * Bb + b0);
      aa[0] = __uint_as_float((unsigned)av.x << 16);
      aa[1] = __uint_as_float((unsigned)av.y << 16);
      aa[2] = __uint_as_float((unsigned)av.z << 16);
      aa[3] = __uint_as_float((unsigned)av.w << 16);
    } else {
      float4 av = *(const float4*)(Af + (size_t)k * Bb + b0);
      aa[0] = av.x; aa[1] = av.y; aa[2] = av.z; aa[3] = av.w;
    }
    float4 uv = *(const float4*)(Wy + (size_t)k * Oo + o0);
    float uu[4] = {uv.x, uv.y, uv.z, uv.w};
#pragma unroll
    for (int i = 0; i < 4; ++i)
#pragma unroll
      for (int j = 0; j < 4; ++j) acc[i][j] += aa[i] * uu[j];
  }

#pragma unroll
  for (int i = 0; i < 4; ++i) {
    float4 v = {acc[i][0], acc[i][1], acc[i][2], acc[i][3]};
    *(float4*)(y + ((size_t)(b0 + i) * Tt + t) * Oo + o0) = v;
  }
}

extern "C" void kernel_launch(void* const* d_in, const int* in_sizes, int n_in,
                              void* d_out, int out_size, void* d_ws, size_t ws_size,
                              hipStream_t stream) {
  const float* x  = (const float*)d_in[0];
  const float* h0 = (const float*)d_in[1];
  const float* c0 = (const float*)d_in[2];
  const float* W0 = (const float*)d_in[3];
  const float* W1 = (const float*)d_in[4];
  const float* W2 = (const float*)d_in[5];
  const float* W3 = (const float*)d_in[6];
  const float* U0 = (const float*)d_in[7];
  const float* U1 = (const float*)d_in[8];
  const float* U2 = (const float*)d_in[9];
  const float* U3 = (const float*)d_in[10];
  const float* bi = (const float*)d_in[11];
  const float* bf_ = (const float*)d_in[12];
  const float* bj = (const float*)d_in[13];
  const float* bo = (const float*)d_in[14];
  const float* Wy = (const float*)d_in[15];
  const float* by = (const float*)d_in[16];
  float* y = (float*)d_out;

  const size_t pk_elems = (size_t)256 * 16384;     // 16 MB each (Uc, Wc)
  const size_t hs_elems = (size_t)Tt * Hh * Bb;    // 16,777,216
  const size_t ht_elems = (size_t)Hh * Bb;         // 65,536
  const size_t needA = (2 * pk_elems + hs_elems + 2 * ht_elems) * 4 + 64;  // 101,187,648
  const size_t needB = 2 * pk_elems * 4 + hs_elems * 2 + 2 * ht_elems * 4 + 64;  // 67,633,216
  // tier: A = packed + fp32 hs; B = packed + bf16 hs; C = direct + bf16 hs
  const int tier = (ws_size >= needA) ? 0 : (ws_size >= needB) ? 1 : 2;

  char* base = (char*)d_ws;
  float *Uc = nullptr, *Wc = nullptr;
  void* hsT;
  float *ht0, *ht1;
  unsigned* bar;
  if (tier <= 1) {
    Uc = (float*)base;
    Wc = Uc + pk_elems;
    hsT = (void*)(Wc + pk_elems);
  } else {
    hsT = (void*)base;
  }
  const size_t hs_bytes = (tier == 0) ? hs_elems * 4 : hs_elems * 2;
  ht0 = (float*)((char*)hsT + hs_bytes);
  ht1 = ht0 + ht_elems;
  bar = (unsigned*)(ht1 + ht_elems);

  hipMemsetAsync(bar, 0, 64, stream);

  if (tier == 0)
    lstm_fused<true, false><<<256, 256, 0, stream>>>(
        x, h0, c0, U0, U1, U2, U3, W0, W1, W2, W3, bi, bf_, bj, bo, hsT, ht0,
        ht1, Uc, Wc, bar);
  else if (tier == 1)
    lstm_fused<true, true><<<256, 256, 0, stream>>>(
        x, h0, c0, U0, U1, U2, U3, W0, W1, W2, W3, bi, bf_, bj, bo, hsT, ht0,
        ht1, Uc, Wc, bar);
  else
    lstm_fused<false, true><<<256, 256, 0, stream>>>(
        x, h0, c0, U0, U1, U2, U3, W0, W1, W2, W3, bi, bf_, bj, bo, hsT, ht0,
        ht1, Uc, Wc, bar);

  dim3 gy(16, 256);
  if (tier == 0)
    y_gemm<false><<<gy, 256, 0, stream>>>(hsT, Wy, by, y);
  else
    y_gemm<true><<<gy, 256, 0, stream>>>(hsT, Wy, by, y);
}

// Round 8
// 24926.796 us; speedup vs baseline: 1.2829x; 1.0233x over previous
//
#include <hip/hip_runtime.h>
#include <math.h>

// LSTM: B=64, T=256, D=H=O=1024. fp32 in/out.
// R8 = R7 resubmitted verbatim (R7 never ran: GPU acquisition timeout).
// R6 was LATENCY-bound (VALUBusy 10%, fp32 packed U+W = 4MB/XCD = all of L2 ->
// thrash at HBM-miss latency, 1 wave/SIMD). Fixes: U packed bf16 (1MB/XCD) +
// W packed fp32 (2MB/XCD) -> 3MB/XCD L2-resident hot set; 512 thr/block
// (2 waves/SIMD) for 2x latency hiding; hierarchical grid barrier.
#define Bb 64
#define Tt 256
#define Dd 1024
#define Hh 1024
#define Oo 1024

// ---------------- hierarchical grid barrier (16 leaves x 16 blocks) ----------
// bar layout (uints): leaf[i] @ i*16 (i<16), root @ 256, gen @ 272.
__device__ __forceinline__ void gbar(unsigned* bar, int leaf) {
  __syncthreads();
  if (threadIdx.x == 0) {
    __threadfence();
    unsigned* leafc = bar + leaf * 16;
    unsigned* rootc = bar + 256;
    unsigned* gen   = bar + 272;
    unsigned g = __hip_atomic_load(gen, __ATOMIC_RELAXED, __HIP_MEMORY_SCOPE_AGENT);
    bool done = false;
    if (__hip_atomic_fetch_add(leafc, 1u, __ATOMIC_ACQ_REL, __HIP_MEMORY_SCOPE_AGENT) == 15u) {
      __hip_atomic_store(leafc, 0u, __ATOMIC_RELAXED, __HIP_MEMORY_SCOPE_AGENT);
      if (__hip_atomic_fetch_add(rootc, 1u, __ATOMIC_ACQ_REL, __HIP_MEMORY_SCOPE_AGENT) == 15u) {
        __hip_atomic_store(rootc, 0u, __ATOMIC_RELAXED, __HIP_MEMORY_SCOPE_AGENT);
        __hip_atomic_store(gen, g + 1u, __ATOMIC_RELEASE, __HIP_MEMORY_SCOPE_AGENT);
        done = true;
      }
    }
    if (!done) {
      unsigned spins = 0;
      while (__hip_atomic_load(gen, __ATOMIC_ACQUIRE, __HIP_MEMORY_SCOPE_AGENT) == g) {
        __builtin_amdgcn_s_sleep(2);
        if (++spins > (1u << 20)) break;  // safety valve: never hang
      }
    }
  }
  __syncthreads();
}

__device__ __forceinline__ unsigned short f32_to_bf16(float f) {
  unsigned u = __float_as_uint(f);
  u += 0x7FFFu + ((u >> 16) & 1u);  // round-to-nearest-even
  return (unsigned short)(u >> 16);
}
__device__ __forceinline__ float blo(unsigned u) { return __uint_as_float(u << 16); }
__device__ __forceinline__ float bhi(unsigned u) { return __uint_as_float(u & 0xFFFF0000u); }

// ---------------- persistent fused recurrence ----------------
// 256 blocks x 512 thr (8 waves/CU). Block nb owns state cols s0=4*nb..+3.
// Wave w: q=w>>1 (gate), kh=w&1 (k-half). Lane: ws=lane>>4 (k-quarter),
// bb=lane&15 (b-quad). Thread k-range: BLOCKED [kh*512+ws*128, +128).
// U packed bf16 [gate][k][4cols] (32KB/block); W packed fp32 [k][16] (64KB).
// Partial sums: shfl_xor(16,32) within wave, kh-pairs summed via LDS G2.
template <bool PACKED>
__global__ __launch_bounds__(512) void lstm_fused(
    const float* __restrict__ x, const float* __restrict__ h0,
    const float* __restrict__ c0,
    const float* __restrict__ U0, const float* __restrict__ U1,
    const float* __restrict__ U2, const float* __restrict__ U3,
    const float* __restrict__ W0, const float* __restrict__ W1,
    const float* __restrict__ W2, const float* __restrict__ W3,
    const float* __restrict__ bi, const float* __restrict__ bf_,
    const float* __restrict__ bj, const float* __restrict__ bo,
    unsigned short* __restrict__ hsT, float* ht0, float* ht1,
    unsigned short* __restrict__ Uc16, float* __restrict__ Wc,
    unsigned* bar) {
  const int nb = blockIdx.x;
  const int s0 = nb << 2;
  const int tid = threadIdx.x;
  const int w = tid >> 6, lane = tid & 63;
  const int q = w >> 1, kh = w & 1;
  const int ws = lane >> 4, bb = lane & 15;
  const int b0 = bb << 2;
  const int kbase = kh * 512 + ws * 128;

  __shared__ float G2[8 * 4 * 68];  // [wave][4 cols][64 b + pad] : 8.7 KB

  unsigned short* __restrict__ Ub16 =
      PACKED ? Uc16 + (size_t)nb * 16384 : nullptr;  // 32 KB bf16
  float* __restrict__ Wb = PACKED ? Wc + (size_t)nb * 16384 : nullptr;  // 64 KB

  if (PACKED) {
    // pack own slices: U -> bf16 [qq][k][4c], W -> fp32 [k][qq*4+c]
#pragma unroll
    for (int it = 0; it < 8; ++it) {
      const int qq = it >> 1;
      const int k = ((it & 1) << 9) + tid;  // 0..1023
      const float* __restrict__ Uq =
          ((qq == 0) ? U0 : (qq == 1) ? U1 : (qq == 2) ? U2 : U3) + s0;
      const float* __restrict__ Wq =
          ((qq == 0) ? W0 : (qq == 1) ? W1 : (qq == 2) ? W2 : W3) + s0;
      float4 uv = *(const float4*)(Uq + (size_t)k * Hh);
      float4 wv = *(const float4*)(Wq + (size_t)k * Hh);
      *(float4*)&Wb[(size_t)k * 16 + qq * 4] = wv;
      ushort4 us = {f32_to_bf16(uv.x), f32_to_bf16(uv.y), f32_to_bf16(uv.z),
                    f32_to_bf16(uv.w)};
      *(ushort4*)&Ub16[((size_t)qq * 1024 + k) * 4] = us;
    }
  }

  // update-phase mapping (tid<256): one (n,b) cell per thread
  const int un = tid >> 6, ub = tid & 63;  // valid when tid<256
  float c = 0.f, bu[4] = {0.f, 0.f, 0.f, 0.f};
  if (tid < 256) {
    c = c0[(size_t)ub * Hh + s0 + un];
    ht0[(size_t)(s0 + un) * Bb + ub] = h0[(size_t)ub * Hh + s0 + un];
    bu[0] = bi[s0 + un]; bu[1] = bf_[s0 + un];
    bu[2] = bj[s0 + un]; bu[3] = bo[s0 + un];
  }

  const int leaf = nb >> 4;
  gbar(bar, leaf);  // publishes packed slices + ht0 (drains vmcnt)

  // direct-path bases (fallback tier only)
  const float* __restrict__ UqD =
      ((q == 0) ? U0 : (q == 1) ? U1 : (q == 2) ? U2 : U3) + s0;
  const float* __restrict__ WqD =
      ((q == 0) ? W0 : (q == 1) ? W1 : (q == 2) ? W2 : W3) + s0;

  // x row pointers (4 b-rows per thread), offset to this thread's k-range
  const float* __restrict__ xr0 = x + ((size_t)(b0 + 0) * Tt) * Dd + kbase;
  const float* __restrict__ xr1 = x + ((size_t)(b0 + 1) * Tt) * Dd + kbase;
  const float* __restrict__ xr2 = x + ((size_t)(b0 + 2) * Tt) * Dd + kbase;
  const float* __restrict__ xr3 = x + ((size_t)(b0 + 3) * Tt) * Dd + kbase;

  for (int t = 0; t < Tt; ++t) {
    const float* __restrict__ A = (t & 1) ? ht1 : ht0;
    float* __restrict__ Anext = (t & 1) ? ht0 : ht1;

    float acc[4][4] = {};  // [j: col][i: b]

    // ---- W part first (x is the cold HBM stream -> overlap its latency) ----
    {
      const size_t xoff = (size_t)t * Dd;
#pragma unroll 4
      for (int jl = 0; jl < 32; ++jl) {
        float a[4][4];  // [i: b][kk]
        *(float4*)a[0] = *(const float4*)(xr0 + xoff + 4 * jl);
        *(float4*)a[1] = *(const float4*)(xr1 + xoff + 4 * jl);
        *(float4*)a[2] = *(const float4*)(xr2 + xoff + 4 * jl);
        *(float4*)a[3] = *(const float4*)(xr3 + xoff + 4 * jl);
        float wv[4][4];  // [kk][jc]
#pragma unroll
        for (int kk = 0; kk < 4; ++kk) {
          const int krow = kbase + 4 * jl + kk;
          if (PACKED)
            *(float4*)wv[kk] = *(const float4*)(Wb + (size_t)krow * 16 + q * 4);
          else
            *(float4*)wv[kk] = *(const float4*)(WqD + (size_t)krow * Hh);
        }
#pragma unroll
        for (int kk = 0; kk < 4; ++kk)
#pragma unroll
          for (int jc = 0; jc < 4; ++jc)
#pragma unroll
            for (int i = 0; i < 4; ++i) acc[jc][i] += a[i][kk] * wv[kk][jc];
      }
    }

    // ---- U part: h @ U over this thread's 128 k-rows ----
    if (PACKED) {
      const float* __restrict__ Ap = A + (size_t)kbase * Bb + b0;
      const uint4* __restrict__ Upq =
          (const uint4*)(Ub16 + ((size_t)q * 1024 + kbase) * 4);
#pragma unroll 8
      for (int k2 = 0; k2 < 64; ++k2) {  // 2 k per iter
        float4 a0 = *(const float4*)Ap;
        float4 a1 = *(const float4*)(Ap + Bb);
        Ap += 2 * Bb;
        uint4 up = Upq[k2];
        float u0[4] = {blo(up.x), bhi(up.x), blo(up.y), bhi(up.y)};
        float u1[4] = {blo(up.z), bhi(up.z), blo(up.w), bhi(up.w)};
        float aa0[4] = {a0.x, a0.y, a0.z, a0.w};
        float aa1[4] = {a1.x, a1.y, a1.z, a1.w};
#pragma unroll
        for (int j = 0; j < 4; ++j)
#pragma unroll
          for (int i = 0; i < 4; ++i)
            acc[j][i] += aa0[i] * u0[j] + aa1[i] * u1[j];
      }
    } else {
      const float* __restrict__ Ap = A + (size_t)kbase * Bb + b0;
      const float* __restrict__ Up = UqD + (size_t)kbase * Hh;
#pragma unroll 8
      for (int k = 0; k < 128; ++k) {
        float4 av = *(const float4*)Ap;
        float4 uv = *(const float4*)Up;
        Ap += Bb;
        Up += Hh;
        float aa[4] = {av.x, av.y, av.z, av.w};
        float uu[4] = {uv.x, uv.y, uv.z, uv.w};
#pragma unroll
        for (int j = 0; j < 4; ++j)
#pragma unroll
          for (int i = 0; i < 4; ++i) acc[j][i] += aa[i] * uu[j];
      }
    }

    // ---- reduce over ws (lane bits 4,5) in-wave ----
#pragma unroll
    for (int j = 0; j < 4; ++j)
#pragma unroll
      for (int i = 0; i < 4; ++i) {
        float v = acc[j][i];
        v += __shfl_xor(v, 16);
        v += __shfl_xor(v, 32);
        acc[j][i] = v;
      }
    if (ws == 0) {
#pragma unroll
      for (int j = 0; j < 4; ++j) {
        float4 v = {acc[j][0], acc[j][1], acc[j][2], acc[j][3]};
        *(float4*)&G2[((size_t)w * 4 + j) * 68 + b0] = v;
      }
    }
    __syncthreads();

    // ---- block-local cell update for (n = s0+un, b = ub), tid<256 ----
    if (tid < 256) {
      float g4[4];
#pragma unroll
      for (int qq = 0; qq < 4; ++qq)
        g4[qq] = G2[((size_t)(qq * 2 + 0) * 4 + un) * 68 + ub] +
                 G2[((size_t)(qq * 2 + 1) * 4 + un) * 68 + ub] + bu[qq];

      float i_ = 1.f / (1.f + __expf(-g4[0]));
      float f_ = 1.f / (1.f + __expf(-g4[1]));
      float j_ = tanhf(g4[2]);
      float o_ = 1.f / (1.f + __expf(-g4[3]));
      c = f_ * c + i_ * j_;
      float h = o_ * tanhf(c);
      Anext[(size_t)(s0 + un) * Bb + ub] = h;
      hsT[((size_t)t * Hh + s0 + un) * Bb + ub] = f32_to_bf16(h);
    }

    gbar(bar, leaf);  // also guards G2 reuse next iter
  }
}

// ---------------- y = hs @ Wy + by (hsT bf16 [t][n][b]) ----------------
__global__ __launch_bounds__(256) void y_gemm(
    const unsigned short* __restrict__ hsT, const float* __restrict__ Wy,
    const float* __restrict__ by, float* __restrict__ y) {
  const int ot = blockIdx.x;  // 0..15
  const int t  = blockIdx.y;  // 0..255
  const int o0 = (ot << 6) + ((threadIdx.x >> 4) << 2);
  const int b0 = (threadIdx.x & 15) << 2;

  float bias[4];
  *(float4*)bias = *(const float4*)(by + o0);
  float acc[4][4];  // [i: b][j: o]
#pragma unroll
  for (int i = 0; i < 4; ++i)
#pragma unroll
    for (int j = 0; j < 4; ++j) acc[i][j] = bias[j];

  const unsigned short* __restrict__ Ah = hsT + (size_t)t * Hh * Bb;
  for (int k = 0; k < Hh; ++k) {
    ushort4 av = *(const ushort4*)(Ah + (size_t)k * Bb + b0);
    float aa[4] = {__uint_as_float((unsigned)av.x << 16),
                   __uint_as_float((unsigned)av.y << 16),
                   __uint_as_float((unsigned)av.z << 16),
                   __uint_as_float((unsigned)av.w << 16)};
    float4 uv = *(const float4*)(Wy + (size_t)k * Oo + o0);
    float uu[4] = {uv.x, uv.y, uv.z, uv.w};
#pragma unroll
    for (int i = 0; i < 4; ++i)
#pragma unroll
      for (int j = 0; j < 4; ++j) acc[i][j] += aa[i] * uu[j];
  }

#pragma unroll
  for (int i = 0; i < 4; ++i) {
    float4 v = {acc[i][0], acc[i][1], acc[i][2], acc[i][3]};
    *(float4*)(y + ((size_t)(b0 + i) * Tt + t) * Oo + o0) = v;
  }
}

extern "C" void kernel_launch(void* const* d_in, const int* in_sizes, int n_in,
                              void* d_out, int out_size, void* d_ws, size_t ws_size,
                              hipStream_t stream) {
  const float* x  = (const float*)d_in[0];
  const float* h0 = (const float*)d_in[1];
  const float* c0 = (const float*)d_in[2];
  const float* W0 = (const float*)d_in[3];
  const float* W1 = (const float*)d_in[4];
  const float* W2 = (const float*)d_in[5];
  const float* W3 = (const float*)d_in[6];
  const float* U0 = (const float*)d_in[7];
  const float* U1 = (const float*)d_in[8];
  const float* U2 = (const float*)d_in[9];
  const float* U3 = (const float*)d_in[10];
  const float* bi = (const float*)d_in[11];
  const float* bf_ = (const float*)d_in[12];
  const float* bj = (const float*)d_in[13];
  const float* bo = (const float*)d_in[14];
  const float* Wy = (const float*)d_in[15];
  const float* by = (const float*)d_in[16];
  float* y = (float*)d_out;

  const size_t uc_elems = (size_t)256 * 16384;   // bf16 -> 8 MB
  const size_t wc_elems = (size_t)256 * 16384;   // fp32 -> 16 MB
  const size_t hs_elems = (size_t)Tt * Hh * Bb;  // bf16 -> 32 MB
  const size_t ht_elems = (size_t)Hh * Bb;
  const size_t need = uc_elems * 2 + wc_elems * 4 + hs_elems * 2 +
                      2 * ht_elems * 4 + 4096;  // ~57 MB
  const bool packed = (ws_size >= need);

  char* base = (char*)d_ws;
  unsigned short* Uc16 = nullptr;
  float* Wc = nullptr;
  unsigned short* hsT;
  if (packed) {
    Uc16 = (unsigned short*)base;
    Wc = (float*)(base + uc_elems * 2);
    hsT = (unsigned short*)(base + uc_elems * 2 + wc_elems * 4);
  } else {
    hsT = (unsigned short*)base;
  }
  float* ht0 = (float*)((char*)hsT + hs_elems * 2);
  float* ht1 = ht0 + ht_elems;
  unsigned* bar = (unsigned*)(ht1 + ht_elems);

  hipMemsetAsync(bar, 0, 2048, stream);

  if (packed)
    lstm_fused<true><<<256, 512, 0, stream>>>(
        x, h0, c0, U0, U1, U2, U3, W0, W1, W2, W3, bi, bf_, bj, bo, hsT, ht0,
        ht1, Uc16, Wc, bar);
  else
    lstm_fused<false><<<256, 512, 0, stream>>>(
        x, h0, c0, U0, U1, U2, U3, W0, W1, W2, W3, bi, bf_, bj, bo, hsT, ht0,
        ht1, Uc16, Wc, bar);

  dim3 gy(16, 256);
  y_gemm<<<gy, 256, 0, stream>>>(hsT, Wy, by, y);
}